// Round 5
// baseline (268.470 us; speedup 1.0000x reference)
//
#include <hip/hip_runtime.h>
#include <stdint.h>

typedef __attribute__((ext_vector_type(8))) short bf16x8;   // 8 bf16 in 4 VGPRs
typedef __attribute__((ext_vector_type(4))) float f32x4;
typedef __attribute__((address_space(1))) void as1_void;
typedef __attribute__((address_space(3))) void as3_void;

#define D_MODEL 1024
#define SEQ     2048
#define BATCH   4
#define HEADS   16
#define HDIM    64

// softmax scale: exp(s/32) = exp2(s * log2e/32); folded into Wq/bq at prep time
#define QSCALE 0.045084220029218407f

__device__ __forceinline__ ushort f2bf(float f) {
  union { float f; unsigned u; } v; v.f = f;
  unsigned u = v.u + 0x7fffu + ((v.u >> 16) & 1u);  // RNE
  return (ushort)(u >> 16);
}

__device__ __forceinline__ void gload_lds16(const void* g, void* l) {
  // width=16: emits global_load_lds_dwordx4; LDS dest = wave-uniform base + lane*16
  __builtin_amdgcn_global_load_lds((as1_void*)(uintptr_t)g, (as3_void*)l, 16, 0, 0);
}

// pack 8 floats -> bf16x8 (truncation) via v_perm
__device__ __forceinline__ bf16x8 pack8(float a0, float a1, float a2, float a3,
                                        float a4, float a5, float a6, float a7) {
  union { uint u[4]; bf16x8 v; } x;
  x.u[0] = __builtin_amdgcn_perm(__float_as_uint(a1), __float_as_uint(a0), 0x07060302);
  x.u[1] = __builtin_amdgcn_perm(__float_as_uint(a3), __float_as_uint(a2), 0x07060302);
  x.u[2] = __builtin_amdgcn_perm(__float_as_uint(a5), __float_as_uint(a4), 0x07060302);
  x.u[3] = __builtin_amdgcn_perm(__float_as_uint(a7), __float_as_uint(a6), 0x07060302);
  return x.v;
}

// ---------- fused prep: X->bf16 | W transpose->bf16 (Wq scaled) | bias concat ----------
__global__ void prep_kernel(const float* __restrict__ X,
                            const float* w0, const float* w1, const float* w2, const float* w3,
                            const float* __restrict__ bq, const float* __restrict__ bk,
                            const float* __restrict__ bv,
                            ushort* __restrict__ Xb, ushort* __restrict__ WT,
                            float* __restrict__ bcat) {
  __shared__ float tile[32][33];
  const int bx = blockIdx.x, t = threadIdx.x;
  if (bx < 8192) {                       // X fp32 -> bf16, 8192*256 float4 groups
    int i = bx * 256 + t;
    float4 f = reinterpret_cast<const float4*>(X)[i];
    ushort4 o;
    o.x = f2bf(f.x); o.y = f2bf(f.y); o.z = f2bf(f.z); o.w = f2bf(f.w);
    reinterpret_cast<ushort4*>(Xb)[i] = o;
  } else if (bx < 12288) {               // weight transpose: 4 weights x 1024 tiles
    int tz = bx - 8192;
    int z = tz >> 10;
    int xy = tz & 1023;
    int bxt = xy & 31, byt = xy >> 5;
    const float* w = (z == 0) ? w0 : (z == 1) ? w1 : (z == 2) ? w2 : w3;
    const float sc = (z == 0) ? QSCALE : 1.0f;
    ushort* o = WT + (size_t)z * D_MODEL * D_MODEL;
    int tx = t & 31, ty = t >> 5;
    int x = bxt * 32 + tx;
    int y0 = byt * 32;
    #pragma unroll
    for (int i = ty; i < 32; i += 8)
      tile[i][tx] = w[(size_t)(y0 + i) * D_MODEL + x];
    __syncthreads();
    #pragma unroll
    for (int i = ty; i < 32; i += 8)
      o[(size_t)(bxt * 32 + i) * D_MODEL + y0 + tx] = f2bf(tile[tx][i] * sc);
  } else {                               // bias concat (12 blocks)
    int i = (bx - 12288) * 256 + t;
    bcat[i] = (i < 1024) ? bq[i] * QSCALE : (i < 2048) ? bk[i - 1024] : bv[i - 2048];
  }
}

#define MFMA16(a, b, c) __builtin_amdgcn_mfma_f32_16x16x32_bf16(a, b, c, 0, 0, 0)

// ---------- generalized 8-phase GEMM template: 256 x BN tiles, K=1024, BK=64 ----------
// 512 threads = 8 waves (2M x 4N); LDS = 2buf x (A 32KB + B BN*128B).
// Grids sized to exact multiples of 256 CUs: BN=192 -> 512 blocks (2 full rounds, no tail);
// BN=128 -> 256 blocks (1 full round).  T2 3-bit XOR swizzle both-sides; T3/T4 counted vmcnt
// (vmcnt(4) @ph1, vmcnt(2) @ph3 -- never 0 in the loop); T5 setprio around MFMA clusters.
// Stage order per K-tile (for tile kt+1): NI==3: [B0,B1 |ph0| B2,A0 |ph1| A2 |ph2| A1,A3 |ph3|]
//                                          NI==2: [B0,B1 |ph0| A0,A2 |ph1| A1 |ph2| A3 |ph3|]
// F32OUT=false: QKV epilogue (Q,K dense bf16 + V permuted transpose), branch per 16-col group
// (2048 % 16 == 0 -> wave-uniform).  F32OUT=true: fp32 C + bias.
template <int BN, bool F32OUT>
__global__ __launch_bounds__(512, 2) void gemm8p(const ushort* __restrict__ A,
                                                 const ushort* __restrict__ BT,
                                                 const float* __restrict__ bias,
                                                 ushort* __restrict__ QK,
                                                 ushort* __restrict__ Vt,
                                                 float* __restrict__ Cf) {
  constexpr int NI = BN / 64;            // B frags per wave = B stage-calls per K-tile
  constexpr int BB = BN * 128;           // B K-tile buffer bytes (BN rows x 64 x 2B)
  constexpr int WCOL = BN / 4;           // cols per wave
  __shared__ __align__(16) char smem[65536 + 2 * BB];   // [0,64K)=A bufs, [64K,..)=B bufs
  const int tid  = threadIdx.x;
  const int w    = tid >> 6;
  const int lane = tid & 63;
  const int lo   = lane & 15, quad = lane >> 4;
  const int wr   = w >> 2, wc = w & 3;

  // XCD-aware bijective swizzle (nwg % 8 == 0 for both instantiations)
  const int nx   = gridDim.x;
  const int nwg  = nx * gridDim.y;
  const int orig = blockIdx.y * nx + blockIdx.x;
  const int wg   = (orig & 7) * (nwg >> 3) + (orig >> 3);
  const int m0   = (wg / nx) * 256;
  const int n0   = (wg % nx) * BN;

  // staging: thread t writes linear LDS chunk t; physical chunk (row, pc) holds logical
  // (row, pc ^ (row&7)) -> global source chunk = tid ^ ((tid>>3)&7)  (XOR in low 3 bits only)
  const int tl = tid ^ ((tid >> 3) & 7);
  const ushort* sA = A  + (size_t)(m0 + (tl >> 3)) * 1024 + (tl & 7) * 8;
  const ushort* sB = BT + (size_t)(n0 + (tl >> 3)) * 1024 + (tl & 7) * 8;
  char* lwA = smem + w * 1024;                 // per-wave stage base (HW adds lane*16)
  char* lwB = smem + 65536 + w * 1024;

  // swizzled ds_read: addr = row*128 + ((ks*64 + quad*16) ^ ((row&7)<<4)); row&7 == lo&7
  const int o0 = (quad * 16) ^ ((lo & 7) << 4);
  const int o1 = o0 ^ 64;
  const int rdA = wr * 16384 + lo * 128;           // + b32A + mi*2048 + o{0,1}
  const int rdB = 65536 + (wc * WCOL + lo) * 128;  // + b32B + ni*2048 + o{0,1}

  f32x4 acc[8][NI];
  #pragma unroll
  for (int i = 0; i < 8; ++i)
    #pragma unroll
    for (int j = 0; j < NI; ++j) acc[i][j] = {0.f, 0.f, 0.f, 0.f};

  // ---- prologue: stage tile 0 into buf 0; order = loop issue order ----
  gload_lds16(sB,               lwB);                  // B0
  gload_lds16(sB +  64 * 1024,  lwB +  8192);          // B1
  if constexpr (NI == 3) gload_lds16(sB + 128 * 1024, lwB + 16384);   // B2
  gload_lds16(sA,               lwA);                  // A0 (rows 0-63)
  gload_lds16(sA + 128 * 1024,  lwA + 16384);          // A2 (rows 128-191)
  gload_lds16(sA +  64 * 1024,  lwA +  8192);          // A1 (rows 64-127)
  gload_lds16(sA + 192 * 1024,  lwA + 24576);          // A3 (rows 192-255)
  asm volatile("s_waitcnt vmcnt(2)" ::: "memory");     // A1,A3 stay in flight (read @ph2/ph3)
  __builtin_amdgcn_s_barrier();
  asm volatile("" ::: "memory");

  const char* L = smem;
  #pragma unroll 2
  for (int kt = 0; kt < 16; ++kt) {
    const int b32A = (kt & 1) << 15;
    const int b32B = (kt & 1) * BB;
    const int nbA  = b32A ^ 32768;
    const int nbB  = b32B ^ BB;
    const int kc   = (kt + 1) * 64;
    const bool pf  = kt < 15;
    bf16x8 bfr[NI][2], af0[2], af1[2];

    // ================ phase 0: all B frags + A mi{0,1}; stage B0,B1 ================
    #pragma unroll
    for (int ni = 0; ni < NI; ++ni) {
      bfr[ni][0] = *(const bf16x8*)(L + b32B + rdB + ni * 2048 + o0);
      bfr[ni][1] = *(const bf16x8*)(L + b32B + rdB + ni * 2048 + o1);
    }
    af0[0] = *(const bf16x8*)(L + b32A + rdA + o0);
    af0[1] = *(const bf16x8*)(L + b32A + rdA + o1);
    af1[0] = *(const bf16x8*)(L + b32A + rdA + 2048 + o0);
    af1[1] = *(const bf16x8*)(L + b32A + rdA + 2048 + o1);
    if (pf) {
      gload_lds16(sB + kc,             lwB + nbB);
      gload_lds16(sB + 64 * 1024 + kc, lwB + nbB + 8192);
    }
    asm volatile("s_waitcnt lgkmcnt(8)" ::: "memory");
    __builtin_amdgcn_s_barrier();
    asm volatile("s_waitcnt lgkmcnt(0)" ::: "memory");
    __builtin_amdgcn_sched_barrier(0);
    __builtin_amdgcn_s_setprio(1);
    #pragma unroll
    for (int ks = 0; ks < 2; ++ks)
      #pragma unroll
      for (int ni = 0; ni < NI; ++ni) {
        acc[0][ni] = MFMA16(af0[ks], bfr[ni][ks], acc[0][ni]);
        acc[1][ni] = MFMA16(af1[ks], bfr[ni][ks], acc[1][ni]);
      }
    __builtin_amdgcn_s_setprio(0);
    __builtin_amdgcn_s_barrier();
    asm volatile("" ::: "memory");

    // ================ phase 1: A mi{2,3}; stage (B2,A0)|(A0,A2); vmcnt(4) ================
    af0[0] = *(const bf16x8*)(L + b32A + rdA + 2 * 2048 + o0);
    af0[1] = *(const bf16x8*)(L + b32A + rdA + 2 * 2048 + o1);
    af1[0] = *(const bf16x8*)(L + b32A + rdA + 3 * 2048 + o0);
    af1[1] = *(const bf16x8*)(L + b32A + rdA + 3 * 2048 + o1);
    if (pf) {
      if constexpr (NI == 3) {
        gload_lds16(sB + 128 * 1024 + kc, lwB + nbB + 16384);
        gload_lds16(sA + kc,              lwA + nbA);
      } else {
        gload_lds16(sA + kc,              lwA + nbA);
        gload_lds16(sA + 128 * 1024 + kc, lwA + nbA + 16384);
      }
    }
    __builtin_amdgcn_s_barrier();
    asm volatile("s_waitcnt lgkmcnt(0)" ::: "memory");
    __builtin_amdgcn_sched_barrier(0);
    __builtin_amdgcn_s_setprio(1);
    #pragma unroll
    for (int ks = 0; ks < 2; ++ks)
      #pragma unroll
      for (int ni = 0; ni < NI; ++ni) {
        acc[2][ni] = MFMA16(af0[ks], bfr[ni][ks], acc[2][ni]);
        acc[3][ni] = MFMA16(af1[ks], bfr[ni][ks], acc[3][ni]);
      }
    __builtin_amdgcn_s_setprio(0);
    if (pf) asm volatile("s_waitcnt vmcnt(4)" ::: "memory");
    else    asm volatile("s_waitcnt vmcnt(0)" ::: "memory");
    __builtin_amdgcn_s_barrier();
    asm volatile("" ::: "memory");

    // ================ phase 2: A mi{4,5}; stage (A2)|(A1) ================
    af0[0] = *(const bf16x8*)(L + b32A + rdA + 4 * 2048 + o0);
    af0[1] = *(const bf16x8*)(L + b32A + rdA + 4 * 2048 + o1);
    af1[0] = *(const bf16x8*)(L + b32A + rdA + 5 * 2048 + o0);
    af1[1] = *(const bf16x8*)(L + b32A + rdA + 5 * 2048 + o1);
    if (pf) {
      if constexpr (NI == 3)
        gload_lds16(sA + 128 * 1024 + kc, lwA + nbA + 16384);
      else
        gload_lds16(sA + 64 * 1024 + kc,  lwA + nbA + 8192);
    }
    __builtin_amdgcn_s_barrier();
    asm volatile("s_waitcnt lgkmcnt(0)" ::: "memory");
    __builtin_amdgcn_sched_barrier(0);
    __builtin_amdgcn_s_setprio(1);
    #pragma unroll
    for (int ks = 0; ks < 2; ++ks)
      #pragma unroll
      for (int ni = 0; ni < NI; ++ni) {
        acc[4][ni] = MFMA16(af0[ks], bfr[ni][ks], acc[4][ni]);
        acc[5][ni] = MFMA16(af1[ks], bfr[ni][ks], acc[5][ni]);
      }
    __builtin_amdgcn_s_setprio(0);
    __builtin_amdgcn_s_barrier();
    asm volatile("" ::: "memory");

    // ================ phase 3: A mi{6,7}; stage (A1,A3)|(A3); vmcnt(2) ================
    af0[0] = *(const bf16x8*)(L + b32A + rdA + 6 * 2048 + o0);
    af0[1] = *(const bf16x8*)(L + b32A + rdA + 6 * 2048 + o1);
    af1[0] = *(const bf16x8*)(L + b32A + rdA + 7 * 2048 + o0);
    af1[1] = *(const bf16x8*)(L + b32A + rdA + 7 * 2048 + o1);
    if (pf) {
      if constexpr (NI == 3) {
        gload_lds16(sA + 64 * 1024 + kc,  lwA + nbA + 8192);
        gload_lds16(sA + 192 * 1024 + kc, lwA + nbA + 24576);
      } else {
        gload_lds16(sA + 192 * 1024 + kc, lwA + nbA + 24576);
      }
    }
    __builtin_amdgcn_s_barrier();
    asm volatile("s_waitcnt lgkmcnt(0)" ::: "memory");
    __builtin_amdgcn_sched_barrier(0);
    __builtin_amdgcn_s_setprio(1);
    #pragma unroll
    for (int ks = 0; ks < 2; ++ks)
      #pragma unroll
      for (int ni = 0; ni < NI; ++ni) {
        acc[6][ni] = MFMA16(af0[ks], bfr[ni][ks], acc[6][ni]);
        acc[7][ni] = MFMA16(af1[ks], bfr[ni][ks], acc[7][ni]);
      }
    __builtin_amdgcn_s_setprio(0);
    if (pf) asm volatile("s_waitcnt vmcnt(2)" ::: "memory");
    __builtin_amdgcn_s_barrier();
    asm volatile("" ::: "memory");
  }

  // ---- epilogue ----
  if constexpr (F32OUT) {
    #pragma unroll
    for (int ni = 0; ni < NI; ++ni) {
      const int col = n0 + wc * WCOL + ni * 16 + lo;
      const float bv = bias[col];
      #pragma unroll
      for (int mi = 0; mi < 8; ++mi) {
        const int row = m0 + wr * 128 + mi * 16 + quad * 4;
        #pragma unroll
        for (int r = 0; r < 4; ++r)
          Cf[(size_t)(row + r) * 1024 + col] = acc[mi][ni][r] + bv;
      }
    }
  } else {
    #pragma unroll
    for (int ni = 0; ni < NI; ++ni) {
      const int colb = n0 + wc * WCOL + ni * 16;   // 16-aligned -> branch wave-uniform
      const float bv = bias[colb + lo];
      if (colb < 2048) {
        // Q,K part: dense [8192][2048] store
        const int col = colb + lo;
        #pragma unroll
        for (int mi = 0; mi < 8; ++mi) {
          const int row = m0 + wr * 128 + mi * 16 + quad * 4;
          #pragma unroll
          for (int r = 0; r < 4; ++r)
            QK[(size_t)(row + r) * 2048 + col] = f2bf(acc[mi][ni][r] + bv);
        }
      } else {
        // V part: permuted-transpose store into Vt[b][h][d][SEQ]
        const int vcol = colb + lo - 2048;
        const int hh = vcol >> 6, d = vcol & 63;
        #pragma unroll
        for (int mi = 0; mi < 8; ++mi) {
          const int base = m0 + wr * 128 + mi * 16;        // multiple of 16
          const int brow = base + quad * 4;                // 4 keys brow..brow+3
          const int bidx = brow >> 11;                     // batch
          const int srow = brow & 2047;                    // seq within batch
          const int ck   = srow >> 6;
          const int c0   = (base & 32) + (quad << 3) + ((base >> 2) & 4);
          ushort e0 = f2bf(acc[mi][ni][0] + bv);
          ushort e1 = f2bf(acc[mi][ni][1] + bv);
          ushort e2 = f2bf(acc[mi][ni][2] + bv);
          ushort e3 = f2bf(acc[mi][ni][3] + bv);
          uint2 pk;
          pk.x = (uint)e0 | ((uint)e1 << 16);
          pk.y = (uint)e2 | ((uint)e3 << 16);
          *(uint2*)&Vt[(size_t)((bidx * HEADS + hh) * HDIM + d) * SEQ + ck * 64 + c0] = pk;
        }
      }
    }
  }
}

// ---------- flash attention: block = 256 q rows, wave = 64 q (4 qg x 16), 64-key chunks ----------
// S^T via mfma(A=K,B=Q); exp'd scores feed PV A-operand directly from registers.
// R5 (T15 att[2] pipeline): PV of chunk ck-1 is deferred into iteration ck, where its MFMA
// cluster (register-only operands afP/vfP) is independent of chunk ck's exp/pack VALU chain
// -> the scheduler interleaves them (MFMA pipe fills the VALU phase). V-fragments for the
// deferred PV are copied LDS->reg in the producing iteration, so the 2-buffer staging and
// counted-vmcnt discipline are unchanged. Peel ck=0; epilogue PV for the last chunk.
__global__ __launch_bounds__(256, 2) void attn_kernel(const ushort* __restrict__ QK,
                                                      const ushort* __restrict__ Vt,
                                                      ushort* __restrict__ Og) {
  __shared__ __align__(16) ushort Ks[2][64 * 64];   // [buf][key][64 d], seg-swizzled
  __shared__ __align__(16) ushort Vs[2][64 * 64];   // [buf][d][64 key-slots], seg-swizzled

  const int tid  = threadIdx.x;
  const int w    = tid >> 6, lane = tid & 63;
  const int lo   = lane & 15, quad = lane >> 4;

  // XCD remap: p -> (G, qb); bijective, p&7 == G&7 (8 q-blocks of a group share an XCD)
  const int p  = blockIdx.x + (blockIdx.y << 3) + (blockIdx.z << 7);
  const int G  = ((p >> 6) << 3) | (p & 7);
  const int h  = G & 15, b = G >> 4;
  const int qbase = ((p >> 3) & 7) * 256 + w * 64;
  const int swz = lo & 7;

  // per-thread staging geometry (4 gload_lds16 per chunk: K0,V0,K1,V1)
  auto STAGE = [&](int buf, int ck) {
    #pragma unroll
    for (int i = 0; i < 2; ++i) {
      const int c16 = (w * 2 + i) * 64 + lane;
      const int r = c16 >> 3, ps = c16 & 7;
      const int gs = ps ^ (r & 7);
      gload_lds16(QK + (size_t)(b * SEQ + ck * 64 + r) * 2048 + 1024 + h * HDIM + gs * 8,
                  &Ks[buf][(w * 2 + i) * 512]);
      gload_lds16(Vt + (size_t)((b * HEADS + h) * HDIM + r) * SEQ + ck * 64 + gs * 8,
                  &Vs[buf][(w * 2 + i) * 512]);
    }
  };

  // Q fragments (B-operand layout: n=lo, k=quad*8+j); pre-scaled by QSCALE via Wq
  bf16x8 qf[4][2];
  #pragma unroll
  for (int qg = 0; qg < 4; ++qg) {
    const ushort* qp = QK + (size_t)(b * SEQ + qbase + qg * 16 + lo) * 2048 + h * HDIM;
    qf[qg][0] = *(const bf16x8*)(qp + quad * 8);
    qf[qg][1] = *(const bf16x8*)(qp + 32 + quad * 8);
  }

  f32x4 acc[4][4];
  #pragma unroll
  for (int qg = 0; qg < 4; ++qg)
    #pragma unroll
    for (int t = 0; t < 4; ++t) acc[qg][t] = {0.f, 0.f, 0.f, 0.f};
  float lsum[4] = {0.f, 0.f, 0.f, 0.f};

  // prologue: stage chunks 0 and 1; wait only for chunk 0 (+Q, older) to land
  STAGE(0, 0);
  STAGE(1, 1);
  asm volatile("s_waitcnt vmcnt(4)" ::: "memory");
  __builtin_amdgcn_s_barrier();
  asm volatile("" ::: "memory");

  bf16x8 afP[4][2];   // exp'd scores of chunk ck-1 (PV A-operands)
  bf16x8 vfP[4][2];   // V fragments of chunk ck-1 (PV B-operands)

  // ---- peel ck = 0: S^T + exp -> afP; V -> vfP (no PV yet) ----
  {
    bf16x8 kf[4][2];
    #pragma unroll
    for (int sub = 0; sub < 4; ++sub) {
      const ushort* kr = &Ks[0][(sub * 16 + lo) * 64];
      kf[sub][0] = *(const bf16x8*)(kr + ((quad ^ swz) * 8));
      kf[sub][1] = *(const bf16x8*)(kr + (((4 + quad) ^ swz) * 8));
    }
    #pragma unroll
    for (int qg = 0; qg < 4; ++qg) {
      f32x4 s[4];
      #pragma unroll
      for (int sub = 0; sub < 4; ++sub) s[sub] = {0.f, 0.f, 0.f, 0.f};
      #pragma unroll
      for (int sub = 0; sub < 4; ++sub) {
        s[sub] = MFMA16(kf[sub][0], qf[qg][0], s[sub]);
        s[sub] = MFMA16(kf[sub][1], qf[qg][1], s[sub]);
      }
      float p2[4][4];
      #pragma unroll
      for (int sub = 0; sub < 4; ++sub)
        #pragma unroll
        for (int r = 0; r < 4; ++r) p2[sub][r] = __builtin_amdgcn_exp2f(s[sub][r]);
      float t0 = 0.f;
      #pragma unroll
      for (int sub = 0; sub < 4; ++sub)
        t0 += (p2[sub][0] + p2[sub][1]) + (p2[sub][2] + p2[sub][3]);
      lsum[qg] += t0;
      afP[qg][0] = pack8(p2[0][0], p2[0][1], p2[0][2], p2[0][3], p2[1][0], p2[1][1], p2[1][2], p2[1][3]);
      afP[qg][1] = pack8(p2[2][0], p2[2][1], p2[2][2], p2[2][3], p2[3][0], p2[3][1], p2[3][2], p2[3][3]);
    }
    #pragma unroll
    for (int t = 0; t < 4; ++t) {
      const ushort* vr = &Vs[0][(t * 16 + lo) * 64];
      #pragma unroll
      for (int hh = 0; hh < 2; ++hh)
        vfP[t][hh] = *(const bf16x8*)(vr + (((hh * 4 + quad) ^ swz) * 8));
    }
  }
  asm volatile("" ::: "memory");
  __builtin_amdgcn_s_barrier();   // buf 0 fully consumed -> restageable
  asm volatile("" ::: "memory");

  #pragma unroll 2
  for (int ck = 1; ck < SEQ / 64; ++ck) {
    const int cur = ck & 1;
    if (ck < SEQ / 64 - 1) {
      STAGE(cur ^ 1, ck + 1);                           // issue-early (T14)
      asm volatile("s_waitcnt vmcnt(4)" ::: "memory");  // wait chunk ck; ck+1 stays in flight
    } else {
      asm volatile("s_waitcnt vmcnt(0)" ::: "memory");
    }
    __builtin_amdgcn_s_barrier();
    asm volatile("" ::: "memory");

    // --- S^T(ck) -> exp/pack(ck) [VALU]  interleaved with  PV(ck-1) [MFMA, regs only] ---
    bf16x8 kf[4][2];
    #pragma unroll
    for (int sub = 0; sub < 4; ++sub) {
      const ushort* kr = &Ks[cur][(sub * 16 + lo) * 64];
      kf[sub][0] = *(const bf16x8*)(kr + ((quad ^ swz) * 8));
      kf[sub][1] = *(const bf16x8*)(kr + (((4 + quad) ^ swz) * 8));
    }

    bf16x8 afC[4][2], vfC[4][2];
    __builtin_amdgcn_s_setprio(1);
    #pragma unroll
    for (int qg = 0; qg < 4; ++qg) {
      f32x4 s[4];
      #pragma unroll
      for (int sub = 0; sub < 4; ++sub) s[sub] = {0.f, 0.f, 0.f, 0.f};
      #pragma unroll
      for (int sub = 0; sub < 4; ++sub) {
        s[sub] = MFMA16(kf[sub][0], qf[qg][0], s[sub]);
        s[sub] = MFMA16(kf[sub][1], qf[qg][1], s[sub]);
      }
      float p2[4][4];
      #pragma unroll
      for (int sub = 0; sub < 4; ++sub)
        #pragma unroll
        for (int r = 0; r < 4; ++r) p2[sub][r] = __builtin_amdgcn_exp2f(s[sub][r]);
      float t0 = 0.f;
      #pragma unroll
      for (int sub = 0; sub < 4; ++sub)
        t0 += (p2[sub][0] + p2[sub][1]) + (p2[sub][2] + p2[sub][3]);
      lsum[qg] += t0;
      afC[qg][0] = pack8(p2[0][0], p2[0][1], p2[0][2], p2[0][3], p2[1][0], p2[1][1], p2[1][2], p2[1][3]);
      afC[qg][1] = pack8(p2[2][0], p2[2][1], p2[2][2], p2[2][3], p2[3][0], p2[3][1], p2[3][2], p2[3][3]);
    }

    // V(ck) -> registers for next iteration's PV
    #pragma unroll
    for (int t = 0; t < 4; ++t) {
      const ushort* vr = &Vs[cur][(t * 16 + lo) * 64];
      #pragma unroll
      for (int hh = 0; hh < 2; ++hh)
        vfC[t][hh] = *(const bf16x8*)(vr + (((hh * 4 + quad) ^ swz) * 8));
    }

    // PV(ck-1): pure register MFMA cluster -- overlaps the exp/pack VALU above
    #pragma unroll
    for (int t = 0; t < 4; ++t)
      #pragma unroll
      for (int hh = 0; hh < 2; ++hh)
        #pragma unroll
        for (int qg = 0; qg < 4; ++qg)
          acc[qg][t] = MFMA16(afP[qg][hh], vfP[t][hh], acc[qg][t]);
    __builtin_amdgcn_s_setprio(0);

    // rotate pipeline state
    #pragma unroll
    for (int qg = 0; qg < 4; ++qg) { afP[qg][0] = afC[qg][0]; afP[qg][1] = afC[qg][1]; }
    #pragma unroll
    for (int t = 0; t < 4; ++t) { vfP[t][0] = vfC[t][0]; vfP[t][1] = vfC[t][1]; }

    asm volatile("" ::: "memory");
    __builtin_amdgcn_s_barrier();   // all LDS reads of buf cur done before it is restaged
    asm volatile("" ::: "memory");
  }

  // ---- epilogue: PV of the last chunk ----
  #pragma unroll
  for (int t = 0; t < 4; ++t)
    #pragma unroll
    for (int hh = 0; hh < 2; ++hh)
      #pragma unroll
      for (int qg = 0; qg < 4; ++qg)
        acc[qg][t] = MFMA16(afP[qg][hh], vfP[t][hh], acc[qg][t]);

  // --- lsum lives at lane lo = q; reduce across quads, redistribute, store ---
  #pragma unroll
  for (int qg = 0; qg < 4; ++qg) {
    float v = lsum[qg];
    v += __shfl_xor(v, 16);
    v += __shfl_xor(v, 32);
    float linv[4];
    #pragma unroll
    for (int r = 0; r < 4; ++r) linv[r] = 1.0f / __shfl(v, quad * 4 + r);
    #pragma unroll
    for (int t = 0; t < 4; ++t)
      #pragma unroll
      for (int r = 0; r < 4; ++r)
        Og[(size_t)(b * SEQ + qbase + qg * 16 + quad * 4 + r) * D_MODEL + h * HDIM + t * 16 + lo] =
            f2bf(acc[qg][t][r] * linv[r]);
  }
}

extern "C" void kernel_launch(void* const* d_in, const int* in_sizes, int n_in,
                              void* d_out, int out_size, void* d_ws, size_t ws_size,
                              hipStream_t stream) {
  const float* X  = (const float*)d_in[0];
  const float* Wq = (const float*)d_in[1];
  const float* bq = (const float*)d_in[2];
  const float* Wk = (const float*)d_in[3];
  const float* bk = (const float*)d_in[4];
  const float* Wv = (const float*)d_in[5];
  const float* bv = (const float*)d_in[6];
  const float* Wo = (const float*)d_in[7];
  const float* bo = (const float*)d_in[8];
  float* out = (float*)d_out;
  char* ws = (char*)d_ws;

  // workspace (88 MB):
  //   [0,16M)   Xb  (bf16 X)
  //   [16,24M)  WT  (4x bf16 transposed weights q|k|v|o; Wq pre-scaled)
  //   [24,56M)  QK  bf16 [8192][2048]
  //   [56,72M)  Vt  bf16 [b][h][64][2048] (permuted keys)
  //   [72,88M)  Ob  bf16 [8192][1024]; head transiently holds bcat (dead before attn writes Ob)
  ushort* Xb  = (ushort*)(ws);
  ushort* WT  = (ushort*)(ws + 16777216);
  ushort* QKb = (ushort*)(ws + 25165824);
  ushort* Vtb = (ushort*)(ws + 58720256);
  ushort* Ob  = (ushort*)(ws + 75497472);
  float*  bcat = (float*)(ws + 75497472);
  const int WSTRIDE = D_MODEL * D_MODEL;

  // 1) fused prep: X->bf16, weight transposes, bias concat
  prep_kernel<<<12300, 256, 0, stream>>>(X, Wq, Wk, Wv, Wo, bq, bk, bv, Xb, WT, bcat);

  // 2) fused QKV projection: 256x192 tiles -> 512 blocks = 2 exact rounds on 256 CUs
  gemm8p<192, false><<<dim3(16, 32), 512, 0, stream>>>(Xb, WT, bcat, QKb, Vtb, nullptr);

  // 3) flash attention (att[2] pipeline + dbuf staging + XCD-grouped K/V reuse)
  attn_kernel<<<dim3(SEQ / 256, HEADS, BATCH), 256, 0, stream>>>(QKb, Vtb, Ob);

  // 4) output projection: 256x128 tiles -> 256 blocks = 1 exact round, fp32 out + bias
  gemm8p<128, true><<<dim3(8, 32), 512, 0, stream>>>(Ob, WT + 3 * WSTRIDE, bo, nullptr, nullptr, out);
}

// Round 6
// 261.783 us; speedup vs baseline: 1.0255x; 1.0255x over previous
//
#include <hip/hip_runtime.h>
#include <stdint.h>

typedef __attribute__((ext_vector_type(8))) short bf16x8;   // 8 bf16 in 4 VGPRs
typedef __attribute__((ext_vector_type(4))) float f32x4;
typedef __attribute__((address_space(1))) void as1_void;
typedef __attribute__((address_space(3))) void as3_void;

#define D_MODEL 1024
#define SEQ     2048
#define BATCH   4
#define HEADS   16
#define HDIM    64

// softmax scale: exp(s/32) = exp2(s * log2e/32); folded into Wq/bq at prep time
#define QSCALE 0.045084220029218407f

__device__ __forceinline__ ushort f2bf(float f) {
  union { float f; unsigned u; } v; v.f = f;
  unsigned u = v.u + 0x7fffu + ((v.u >> 16) & 1u);  // RNE
  return (ushort)(u >> 16);
}

__device__ __forceinline__ void gload_lds16(const void* g, void* l) {
  // width=16: emits global_load_lds_dwordx4; LDS dest = wave-uniform base + lane*16
  __builtin_amdgcn_global_load_lds((as1_void*)(uintptr_t)g, (as3_void*)l, 16, 0, 0);
}

// pack 8 floats -> bf16x8 (truncation) via v_perm
__device__ __forceinline__ bf16x8 pack8(float a0, float a1, float a2, float a3,
                                        float a4, float a5, float a6, float a7) {
  union { uint u[4]; bf16x8 v; } x;
  x.u[0] = __builtin_amdgcn_perm(__float_as_uint(a1), __float_as_uint(a0), 0x07060302);
  x.u[1] = __builtin_amdgcn_perm(__float_as_uint(a3), __float_as_uint(a2), 0x07060302);
  x.u[2] = __builtin_amdgcn_perm(__float_as_uint(a5), __float_as_uint(a4), 0x07060302);
  x.u[3] = __builtin_amdgcn_perm(__float_as_uint(a7), __float_as_uint(a6), 0x07060302);
  return x.v;
}

// ---------- fused prep: X->bf16 | W transpose->bf16 (Wq scaled) | bias concat ----------
__global__ void prep_kernel(const float* __restrict__ X,
                            const float* w0, const float* w1, const float* w2, const float* w3,
                            const float* __restrict__ bq, const float* __restrict__ bk,
                            const float* __restrict__ bv,
                            ushort* __restrict__ Xb, ushort* __restrict__ WT,
                            float* __restrict__ bcat) {
  __shared__ float tile[32][33];
  const int bx = blockIdx.x, t = threadIdx.x;
  if (bx < 8192) {                       // X fp32 -> bf16, 8192*256 float4 groups
    int i = bx * 256 + t;
    float4 f = reinterpret_cast<const float4*>(X)[i];
    ushort4 o;
    o.x = f2bf(f.x); o.y = f2bf(f.y); o.z = f2bf(f.z); o.w = f2bf(f.w);
    reinterpret_cast<ushort4*>(Xb)[i] = o;
  } else if (bx < 12288) {               // weight transpose: 4 weights x 1024 tiles
    int tz = bx - 8192;
    int z = tz >> 10;
    int xy = tz & 1023;
    int bxt = xy & 31, byt = xy >> 5;
    const float* w = (z == 0) ? w0 : (z == 1) ? w1 : (z == 2) ? w2 : w3;
    const float sc = (z == 0) ? QSCALE : 1.0f;
    ushort* o = WT + (size_t)z * D_MODEL * D_MODEL;
    int tx = t & 31, ty = t >> 5;
    int x = bxt * 32 + tx;
    int y0 = byt * 32;
    #pragma unroll
    for (int i = ty; i < 32; i += 8)
      tile[i][tx] = w[(size_t)(y0 + i) * D_MODEL + x];
    __syncthreads();
    #pragma unroll
    for (int i = ty; i < 32; i += 8)
      o[(size_t)(bxt * 32 + i) * D_MODEL + y0 + tx] = f2bf(tile[tx][i] * sc);
  } else {                               // bias concat (12 blocks)
    int i = (bx - 12288) * 256 + t;
    bcat[i] = (i < 1024) ? bq[i] * QSCALE : (i < 2048) ? bk[i - 1024] : bv[i - 2048];
  }
}

#define MFMA16(a, b, c) __builtin_amdgcn_mfma_f32_16x16x32_bf16(a, b, c, 0, 0, 0)

// ---------- generalized 8-phase GEMM template: 256 x BN tiles, K=1024, BK=64 ----------
// 512 threads = 8 waves (2M x 4N); LDS = 2buf x (A 32KB + B BN*128B).
// Grids sized to exact multiples of 256 CUs: BN=192 -> 512 blocks (2 full rounds, no tail);
// BN=128 -> 256 blocks (1 full round).  T2 3-bit XOR swizzle both-sides; T3/T4 counted vmcnt
// (vmcnt(4) @ph1, vmcnt(2) @ph3 -- never 0 in the loop); T5 setprio around MFMA clusters.
// Stage order per K-tile (for tile kt+1): NI==3: [B0,B1 |ph0| B2,A0 |ph1| A2 |ph2| A1,A3 |ph3|]
//                                          NI==2: [B0,B1 |ph0| A0,A2 |ph1| A1 |ph2| A3 |ph3|]
// F32OUT=false: QKV epilogue (Q,K dense bf16 + V permuted transpose), branch per 16-col group
// (2048 % 16 == 0 -> wave-uniform).  F32OUT=true: fp32 C + bias.
template <int BN, bool F32OUT>
__global__ __launch_bounds__(512, 2) void gemm8p(const ushort* __restrict__ A,
                                                 const ushort* __restrict__ BT,
                                                 const float* __restrict__ bias,
                                                 ushort* __restrict__ QK,
                                                 ushort* __restrict__ Vt,
                                                 float* __restrict__ Cf) {
  constexpr int NI = BN / 64;            // B frags per wave = B stage-calls per K-tile
  constexpr int BB = BN * 128;           // B K-tile buffer bytes (BN rows x 64 x 2B)
  constexpr int WCOL = BN / 4;           // cols per wave
  __shared__ __align__(16) char smem[65536 + 2 * BB];   // [0,64K)=A bufs, [64K,..)=B bufs
  const int tid  = threadIdx.x;
  const int w    = tid >> 6;
  const int lane = tid & 63;
  const int lo   = lane & 15, quad = lane >> 4;
  const int wr   = w >> 2, wc = w & 3;

  // XCD-aware bijective swizzle (nwg % 8 == 0 for both instantiations)
  const int nx   = gridDim.x;
  const int nwg  = nx * gridDim.y;
  const int orig = blockIdx.y * nx + blockIdx.x;
  const int wg   = (orig & 7) * (nwg >> 3) + (orig >> 3);
  const int m0   = (wg / nx) * 256;
  const int n0   = (wg % nx) * BN;

  // staging: thread t writes linear LDS chunk t; physical chunk (row, pc) holds logical
  // (row, pc ^ (row&7)) -> global source chunk = tid ^ ((tid>>3)&7)  (XOR in low 3 bits only)
  const int tl = tid ^ ((tid >> 3) & 7);
  const ushort* sA = A  + (size_t)(m0 + (tl >> 3)) * 1024 + (tl & 7) * 8;
  const ushort* sB = BT + (size_t)(n0 + (tl >> 3)) * 1024 + (tl & 7) * 8;
  char* lwA = smem + w * 1024;                 // per-wave stage base (HW adds lane*16)
  char* lwB = smem + 65536 + w * 1024;

  // swizzled ds_read: addr = row*128 + ((ks*64 + quad*16) ^ ((row&7)<<4)); row&7 == lo&7
  const int o0 = (quad * 16) ^ ((lo & 7) << 4);
  const int o1 = o0 ^ 64;
  const int rdA = wr * 16384 + lo * 128;           // + b32A + mi*2048 + o{0,1}
  const int rdB = 65536 + (wc * WCOL + lo) * 128;  // + b32B + ni*2048 + o{0,1}

  f32x4 acc[8][NI];
  #pragma unroll
  for (int i = 0; i < 8; ++i)
    #pragma unroll
    for (int j = 0; j < NI; ++j) acc[i][j] = {0.f, 0.f, 0.f, 0.f};

  // ---- prologue: stage tile 0 into buf 0; order = loop issue order ----
  gload_lds16(sB,               lwB);                  // B0
  gload_lds16(sB +  64 * 1024,  lwB +  8192);          // B1
  if constexpr (NI == 3) gload_lds16(sB + 128 * 1024, lwB + 16384);   // B2
  gload_lds16(sA,               lwA);                  // A0 (rows 0-63)
  gload_lds16(sA + 128 * 1024,  lwA + 16384);          // A2 (rows 128-191)
  gload_lds16(sA +  64 * 1024,  lwA +  8192);          // A1 (rows 64-127)
  gload_lds16(sA + 192 * 1024,  lwA + 24576);          // A3 (rows 192-255)
  asm volatile("s_waitcnt vmcnt(2)" ::: "memory");     // A1,A3 stay in flight (read @ph2/ph3)
  __builtin_amdgcn_s_barrier();
  asm volatile("" ::: "memory");

  const char* L = smem;
  #pragma unroll 2
  for (int kt = 0; kt < 16; ++kt) {
    const int b32A = (kt & 1) << 15;
    const int b32B = (kt & 1) * BB;
    const int nbA  = b32A ^ 32768;
    const int nbB  = b32B ^ BB;
    const int kc   = (kt + 1) * 64;
    const bool pf  = kt < 15;
    bf16x8 bfr[NI][2], af0[2], af1[2];

    // ================ phase 0: all B frags + A mi{0,1}; stage B0,B1 ================
    #pragma unroll
    for (int ni = 0; ni < NI; ++ni) {
      bfr[ni][0] = *(const bf16x8*)(L + b32B + rdB + ni * 2048 + o0);
      bfr[ni][1] = *(const bf16x8*)(L + b32B + rdB + ni * 2048 + o1);
    }
    af0[0] = *(const bf16x8*)(L + b32A + rdA + o0);
    af0[1] = *(const bf16x8*)(L + b32A + rdA + o1);
    af1[0] = *(const bf16x8*)(L + b32A + rdA + 2048 + o0);
    af1[1] = *(const bf16x8*)(L + b32A + rdA + 2048 + o1);
    if (pf) {
      gload_lds16(sB + kc,             lwB + nbB);
      gload_lds16(sB + 64 * 1024 + kc, lwB + nbB + 8192);
    }
    asm volatile("s_waitcnt lgkmcnt(8)" ::: "memory");
    __builtin_amdgcn_s_barrier();
    asm volatile("s_waitcnt lgkmcnt(0)" ::: "memory");
    __builtin_amdgcn_sched_barrier(0);
    __builtin_amdgcn_s_setprio(1);
    #pragma unroll
    for (int ks = 0; ks < 2; ++ks)
      #pragma unroll
      for (int ni = 0; ni < NI; ++ni) {
        acc[0][ni] = MFMA16(af0[ks], bfr[ni][ks], acc[0][ni]);
        acc[1][ni] = MFMA16(af1[ks], bfr[ni][ks], acc[1][ni]);
      }
    __builtin_amdgcn_s_setprio(0);
    __builtin_amdgcn_s_barrier();
    asm volatile("" ::: "memory");

    // ================ phase 1: A mi{2,3}; stage (B2,A0)|(A0,A2); vmcnt(4) ================
    af0[0] = *(const bf16x8*)(L + b32A + rdA + 2 * 2048 + o0);
    af0[1] = *(const bf16x8*)(L + b32A + rdA + 2 * 2048 + o1);
    af1[0] = *(const bf16x8*)(L + b32A + rdA + 3 * 2048 + o0);
    af1[1] = *(const bf16x8*)(L + b32A + rdA + 3 * 2048 + o1);
    if (pf) {
      if constexpr (NI == 3) {
        gload_lds16(sB + 128 * 1024 + kc, lwB + nbB + 16384);
        gload_lds16(sA + kc,              lwA + nbA);
      } else {
        gload_lds16(sA + kc,              lwA + nbA);
        gload_lds16(sA + 128 * 1024 + kc, lwA + nbA + 16384);
      }
    }
    __builtin_amdgcn_s_barrier();
    asm volatile("s_waitcnt lgkmcnt(0)" ::: "memory");
    __builtin_amdgcn_sched_barrier(0);
    __builtin_amdgcn_s_setprio(1);
    #pragma unroll
    for (int ks = 0; ks < 2; ++ks)
      #pragma unroll
      for (int ni = 0; ni < NI; ++ni) {
        acc[2][ni] = MFMA16(af0[ks], bfr[ni][ks], acc[2][ni]);
        acc[3][ni] = MFMA16(af1[ks], bfr[ni][ks], acc[3][ni]);
      }
    __builtin_amdgcn_s_setprio(0);
    if (pf) asm volatile("s_waitcnt vmcnt(4)" ::: "memory");
    else    asm volatile("s_waitcnt vmcnt(0)" ::: "memory");
    __builtin_amdgcn_s_barrier();
    asm volatile("" ::: "memory");

    // ================ phase 2: A mi{4,5}; stage (A2)|(A1) ================
    af0[0] = *(const bf16x8*)(L + b32A + rdA + 4 * 2048 + o0);
    af0[1] = *(const bf16x8*)(L + b32A + rdA + 4 * 2048 + o1);
    af1[0] = *(const bf16x8*)(L + b32A + rdA + 5 * 2048 + o0);
    af1[1] = *(const bf16x8*)(L + b32A + rdA + 5 * 2048 + o1);
    if (pf) {
      if constexpr (NI == 3)
        gload_lds16(sA + 128 * 1024 + kc, lwA + nbA + 16384);
      else
        gload_lds16(sA + 64 * 1024 + kc,  lwA + nbA + 8192);
    }
    __builtin_amdgcn_s_barrier();
    asm volatile("s_waitcnt lgkmcnt(0)" ::: "memory");
    __builtin_amdgcn_sched_barrier(0);
    __builtin_amdgcn_s_setprio(1);
    #pragma unroll
    for (int ks = 0; ks < 2; ++ks)
      #pragma unroll
      for (int ni = 0; ni < NI; ++ni) {
        acc[4][ni] = MFMA16(af0[ks], bfr[ni][ks], acc[4][ni]);
        acc[5][ni] = MFMA16(af1[ks], bfr[ni][ks], acc[5][ni]);
      }
    __builtin_amdgcn_s_setprio(0);
    __builtin_amdgcn_s_barrier();
    asm volatile("" ::: "memory");

    // ================ phase 3: A mi{6,7}; stage (A1,A3)|(A3); vmcnt(2) ================
    af0[0] = *(const bf16x8*)(L + b32A + rdA + 6 * 2048 + o0);
    af0[1] = *(const bf16x8*)(L + b32A + rdA + 6 * 2048 + o1);
    af1[0] = *(const bf16x8*)(L + b32A + rdA + 7 * 2048 + o0);
    af1[1] = *(const bf16x8*)(L + b32A + rdA + 7 * 2048 + o1);
    if (pf) {
      if constexpr (NI == 3) {
        gload_lds16(sA + 64 * 1024 + kc,  lwA + nbA + 8192);
        gload_lds16(sA + 192 * 1024 + kc, lwA + nbA + 24576);
      } else {
        gload_lds16(sA + 192 * 1024 + kc, lwA + nbA + 24576);
      }
    }
    __builtin_amdgcn_s_barrier();
    asm volatile("s_waitcnt lgkmcnt(0)" ::: "memory");
    __builtin_amdgcn_sched_barrier(0);
    __builtin_amdgcn_s_setprio(1);
    #pragma unroll
    for (int ks = 0; ks < 2; ++ks)
      #pragma unroll
      for (int ni = 0; ni < NI; ++ni) {
        acc[6][ni] = MFMA16(af0[ks], bfr[ni][ks], acc[6][ni]);
        acc[7][ni] = MFMA16(af1[ks], bfr[ni][ks], acc[7][ni]);
      }
    __builtin_amdgcn_s_setprio(0);
    if (pf) asm volatile("s_waitcnt vmcnt(2)" ::: "memory");
    __builtin_amdgcn_s_barrier();
    asm volatile("" ::: "memory");
  }

  // ---- epilogue ----
  if constexpr (F32OUT) {
    #pragma unroll
    for (int ni = 0; ni < NI; ++ni) {
      const int col = n0 + wc * WCOL + ni * 16 + lo;
      const float bv = bias[col];
      #pragma unroll
      for (int mi = 0; mi < 8; ++mi) {
        const int row = m0 + wr * 128 + mi * 16 + quad * 4;
        #pragma unroll
        for (int r = 0; r < 4; ++r)
          Cf[(size_t)(row + r) * 1024 + col] = acc[mi][ni][r] + bv;
      }
    }
  } else {
    #pragma unroll
    for (int ni = 0; ni < NI; ++ni) {
      const int colb = n0 + wc * WCOL + ni * 16;   // 16-aligned -> branch wave-uniform
      const float bv = bias[colb + lo];
      if (colb < 2048) {
        // Q,K part: dense [8192][2048] store
        const int col = colb + lo;
        #pragma unroll
        for (int mi = 0; mi < 8; ++mi) {
          const int row = m0 + wr * 128 + mi * 16 + quad * 4;
          #pragma unroll
          for (int r = 0; r < 4; ++r)
            QK[(size_t)(row + r) * 2048 + col] = f2bf(acc[mi][ni][r] + bv);
        }
      } else {
        // V part: permuted-transpose store into Vt[b][h][d][SEQ]
        const int vcol = colb + lo - 2048;
        const int hh = vcol >> 6, d = vcol & 63;
        #pragma unroll
        for (int mi = 0; mi < 8; ++mi) {
          const int base = m0 + wr * 128 + mi * 16;        // multiple of 16
          const int brow = base + quad * 4;                // 4 keys brow..brow+3
          const int bidx = brow >> 11;                     // batch
          const int srow = brow & 2047;                    // seq within batch
          const int ck   = srow >> 6;
          const int c0   = (base & 32) + (quad << 3) + ((base >> 2) & 4);
          ushort e0 = f2bf(acc[mi][ni][0] + bv);
          ushort e1 = f2bf(acc[mi][ni][1] + bv);
          ushort e2 = f2bf(acc[mi][ni][2] + bv);
          ushort e3 = f2bf(acc[mi][ni][3] + bv);
          uint2 pk;
          pk.x = (uint)e0 | ((uint)e1 << 16);
          pk.y = (uint)e2 | ((uint)e3 << 16);
          *(uint2*)&Vt[(size_t)((bidx * HEADS + hh) * HDIM + d) * SEQ + ck * 64 + c0] = pk;
        }
      }
    }
  }
}

// ---------- flash attention: block = 128 q rows (4 waves x 32 q), 64-key chunks ----------
// R6: R4 structure (dbuf staging + counted vmcnt + XCD grouping), but per-wave q-tile halved
// (2 qg instead of 4) and grid doubled to 1024 blocks -> __launch_bounds__(256,4) gives
// 4 blocks/CU = 16 waves/CU = 4 waves/SIMD (was 2). The within-wave S^T -> exp/pack -> PV
// chain serializes MFMA and VALU pipes; extra waves let the SIMD overlap them across waves.
// Per-wave VGPR state drops ~48 regs (qf, acc halve) -> fits the 128-reg/4-wave budget.
__global__ __launch_bounds__(256, 4) void attn_kernel(const ushort* __restrict__ QK,
                                                      const ushort* __restrict__ Vt,
                                                      ushort* __restrict__ Og) {
  __shared__ __align__(16) ushort Ks[2][64 * 64];   // [buf][key][64 d], seg-swizzled
  __shared__ __align__(16) ushort Vs[2][64 * 64];   // [buf][d][64 key-slots], seg-swizzled

  const int tid  = threadIdx.x;
  const int w    = tid >> 6, lane = tid & 63;
  const int lo   = lane & 15, quad = lane >> 4;

  // XCD remap: p in [0,1024) -> (G, qb); bijective, p&7 == G&7
  // (all 16 q-blocks of group G = b*16+h land on the same XCD; K/V fetched once per XCD L2)
  const int p  = blockIdx.x + (blockIdx.y << 3) + (blockIdx.z << 7);
  const int G  = ((p >> 7) << 3) | (p & 7);
  const int h  = G & 15, b = G >> 4;
  const int qbase = ((p >> 3) & 15) * 128 + w * 32;
  const int swz = lo & 7;

  // per-thread staging geometry (4 gload_lds16 per chunk: K0,V0,K1,V1)
  auto STAGE = [&](int buf, int ck) {
    #pragma unroll
    for (int i = 0; i < 2; ++i) {
      const int c16 = (w * 2 + i) * 64 + lane;
      const int r = c16 >> 3, ps = c16 & 7;
      const int gs = ps ^ (r & 7);
      gload_lds16(QK + (size_t)(b * SEQ + ck * 64 + r) * 2048 + 1024 + h * HDIM + gs * 8,
                  &Ks[buf][(w * 2 + i) * 512]);
      gload_lds16(Vt + (size_t)((b * HEADS + h) * HDIM + r) * SEQ + ck * 64 + gs * 8,
                  &Vs[buf][(w * 2 + i) * 512]);
    }
  };

  // Q fragments (B-operand layout: n=lo, k=quad*8+j); pre-scaled by QSCALE via Wq
  bf16x8 qf[2][2];
  #pragma unroll
  for (int qg = 0; qg < 2; ++qg) {
    const ushort* qp = QK + (size_t)(b * SEQ + qbase + qg * 16 + lo) * 2048 + h * HDIM;
    qf[qg][0] = *(const bf16x8*)(qp + quad * 8);
    qf[qg][1] = *(const bf16x8*)(qp + 32 + quad * 8);
  }

  f32x4 acc[2][4];
  #pragma unroll
  for (int qg = 0; qg < 2; ++qg)
    #pragma unroll
    for (int t = 0; t < 4; ++t) acc[qg][t] = {0.f, 0.f, 0.f, 0.f};
  float lsum[2] = {0.f, 0.f};

  // prologue: stage chunk 0 into buf 0; drain everything (incl. Q loads) once
  STAGE(0, 0);
  __syncthreads();

  #pragma unroll 2
  for (int ck = 0; ck < SEQ / 64; ++ck) {
    const int cur = ck & 1;
    if (ck < SEQ / 64 - 1) {
      STAGE(cur ^ 1, ck + 1);                           // issue-early (T14)
      asm volatile("s_waitcnt vmcnt(4)" ::: "memory");  // wait cur; next stays in flight
    } else {
      asm volatile("s_waitcnt vmcnt(0)" ::: "memory");
    }
    __builtin_amdgcn_s_barrier();
    asm volatile("" ::: "memory");

    // --- phase A: K fragments resident, S^T per q-group, exp + pack in registers ---
    bf16x8 kf[4][2];
    #pragma unroll
    for (int sub = 0; sub < 4; ++sub) {
      const ushort* kr = &Ks[cur][(sub * 16 + lo) * 64];
      kf[sub][0] = *(const bf16x8*)(kr + ((quad ^ swz) * 8));
      kf[sub][1] = *(const bf16x8*)(kr + (((4 + quad) ^ swz) * 8));
    }

    bf16x8 af[2][2];
    #pragma unroll
    for (int qg = 0; qg < 2; ++qg) {
      f32x4 s[4];
      #pragma unroll
      for (int sub = 0; sub < 4; ++sub) s[sub] = {0.f, 0.f, 0.f, 0.f};
      #pragma unroll
      for (int sub = 0; sub < 4; ++sub) {
        s[sub] = MFMA16(kf[sub][0], qf[qg][0], s[sub]);
        s[sub] = MFMA16(kf[sub][1], qf[qg][1], s[sub]);
      }
      float p2[4][4];
      #pragma unroll
      for (int sub = 0; sub < 4; ++sub)
        #pragma unroll
        for (int r = 0; r < 4; ++r) p2[sub][r] = __builtin_amdgcn_exp2f(s[sub][r]);
      float t0 = 0.f;
      #pragma unroll
      for (int sub = 0; sub < 4; ++sub)
        t0 += (p2[sub][0] + p2[sub][1]) + (p2[sub][2] + p2[sub][3]);
      lsum[qg] += t0;
      af[qg][0] = pack8(p2[0][0], p2[0][1], p2[0][2], p2[0][3], p2[1][0], p2[1][1], p2[1][2], p2[1][3]);
      af[qg][1] = pack8(p2[2][0], p2[2][1], p2[2][2], p2[2][3], p2[3][0], p2[3][1], p2[3][2], p2[3][3]);
    }

    // --- phase B: PV (A = exp'd scores from registers, B = V^T from LDS) ---
    __builtin_amdgcn_s_setprio(1);
    #pragma unroll
    for (int t = 0; t < 4; ++t) {
      const ushort* vr = &Vs[cur][(t * 16 + lo) * 64];
      #pragma unroll
      for (int hh = 0; hh < 2; ++hh) {
        bf16x8 vf = *(const bf16x8*)(vr + (((hh * 4 + quad) ^ swz) * 8));
        #pragma unroll
        for (int qg = 0; qg < 2; ++qg)
          acc[qg][t] = MFMA16(af[qg][hh], vf, acc[qg][t]);
      }
    }
    __builtin_amdgcn_s_setprio(0);

    asm volatile("" ::: "memory");
    __builtin_amdgcn_s_barrier();   // all reads of buf cur done before it is restaged
    asm volatile("" ::: "memory");
  }

  // --- epilogue: lsum lives at lane lo = q; reduce across quads, redistribute, store ---
  #pragma unroll
  for (int qg = 0; qg < 2; ++qg) {
    float v = lsum[qg];
    v += __shfl_xor(v, 16);
    v += __shfl_xor(v, 32);
    float linv[4];
    #pragma unroll
    for (int r = 0; r < 4; ++r) linv[r] = 1.0f / __shfl(v, quad * 4 + r);
    #pragma unroll
    for (int t = 0; t < 4; ++t)
      #pragma unroll
      for (int r = 0; r < 4; ++r)
        Og[(size_t)(b * SEQ + qbase + qg * 16 + quad * 4 + r) * D_MODEL + h * HDIM + t * 16 + lo] =
            f2bf(acc[qg][t][r] * linv[r]);
  }
}

extern "C" void kernel_launch(void* const* d_in, const int* in_sizes, int n_in,
                              void* d_out, int out_size, void* d_ws, size_t ws_size,
                              hipStream_t stream) {
  const float* X  = (const float*)d_in[0];
  const float* Wq = (const float*)d_in[1];
  const float* bq = (const float*)d_in[2];
  const float* Wk = (const float*)d_in[3];
  const float* bk = (const float*)d_in[4];
  const float* Wv = (const float*)d_in[5];
  const float* bv = (const float*)d_in[6];
  const float* Wo = (const float*)d_in[7];
  const float* bo = (const float*)d_in[8];
  float* out = (float*)d_out;
  char* ws = (char*)d_ws;

  // workspace (88 MB):
  //   [0,16M)   Xb  (bf16 X)
  //   [16,24M)  WT  (4x bf16 transposed weights q|k|v|o; Wq pre-scaled)
  //   [24,56M)  QK  bf16 [8192][2048]
  //   [56,72M)  Vt  bf16 [b][h][64][2048] (permuted keys)
  //   [72,88M)  Ob  bf16 [8192][1024]; head transiently holds bcat (dead before attn writes Ob)
  ushort* Xb  = (ushort*)(ws);
  ushort* WT  = (ushort*)(ws + 16777216);
  ushort* QKb = (ushort*)(ws + 25165824);
  ushort* Vtb = (ushort*)(ws + 58720256);
  ushort* Ob  = (ushort*)(ws + 75497472);
  float*  bcat = (float*)(ws + 75497472);
  const int WSTRIDE = D_MODEL * D_MODEL;

  // 1) fused prep: X->bf16, weight transposes, bias concat
  prep_kernel<<<12300, 256, 0, stream>>>(X, Wq, Wk, Wv, Wo, bq, bk, bv, Xb, WT, bcat);

  // 2) fused QKV projection: 256x192 tiles -> 512 blocks = 2 exact rounds on 256 CUs
  gemm8p<192, false><<<dim3(16, 32), 512, 0, stream>>>(Xb, WT, bcat, QKb, Vtb, nullptr);

  // 3) flash attention: 1024 blocks (128 q each) -> 4 blocks/CU, 4 waves/SIMD
  attn_kernel<<<dim3(8, 16, 8), 256, 0, stream>>>(QKb, Vtb, Ob);

  // 4) output projection: 256x128 tiles -> 256 blocks = 1 exact round, fp32 out + bias
  gemm8p<128, true><<<dim3(8, 32), 512, 0, stream>>>(Ob, WT + 3 * WSTRIDE, bo, nullptr, nullptr, out);
}

// Round 7
// 239.722 us; speedup vs baseline: 1.1199x; 1.0920x over previous
//
#include <hip/hip_runtime.h>
#include <stdint.h>

typedef __attribute__((ext_vector_type(8))) short bf16x8;   // 8 bf16 in 4 VGPRs
typedef __attribute__((ext_vector_type(4))) float f32x4;
typedef __attribute__((address_space(1))) void as1_void;
typedef __attribute__((address_space(3))) void as3_void;

#define D_MODEL 1024
#define SEQ     2048
#define BATCH   4
#define HEADS   16
#define HDIM    64

// softmax scale: exp(s/32) = exp2(s * log2e/32); folded into Wq/bq at prep time
#define QSCALE 0.045084220029218407f

__device__ __forceinline__ ushort f2bf(float f) {
  union { float f; unsigned u; } v; v.f = f;
  unsigned u = v.u + 0x7fffu + ((v.u >> 16) & 1u);  // RNE
  return (ushort)(u >> 16);
}

__device__ __forceinline__ void gload_lds16(const void* g, void* l) {
  // width=16: emits global_load_lds_dwordx4; LDS dest = wave-uniform base + lane*16
  __builtin_amdgcn_global_load_lds((as1_void*)(uintptr_t)g, (as3_void*)l, 16, 0, 0);
}

// pack 8 floats -> bf16x8 (truncation) via v_perm
__device__ __forceinline__ bf16x8 pack8(float a0, float a1, float a2, float a3,
                                        float a4, float a5, float a6, float a7) {
  union { uint u[4]; bf16x8 v; } x;
  x.u[0] = __builtin_amdgcn_perm(__float_as_uint(a1), __float_as_uint(a0), 0x07060302);
  x.u[1] = __builtin_amdgcn_perm(__float_as_uint(a3), __float_as_uint(a2), 0x07060302);
  x.u[2] = __builtin_amdgcn_perm(__float_as_uint(a5), __float_as_uint(a4), 0x07060302);
  x.u[3] = __builtin_amdgcn_perm(__float_as_uint(a7), __float_as_uint(a6), 0x07060302);
  return x.v;
}

// ---------- fused prep: X->bf16 | W transpose->bf16 (Wq scaled) | bias concat ----------
__global__ void prep_kernel(const float* __restrict__ X,
                            const float* w0, const float* w1, const float* w2, const float* w3,
                            const float* __restrict__ bq, const float* __restrict__ bk,
                            const float* __restrict__ bv,
                            ushort* __restrict__ Xb, ushort* __restrict__ WT,
                            float* __restrict__ bcat) {
  __shared__ float tile[32][33];
  const int bx = blockIdx.x, t = threadIdx.x;
  if (bx < 8192) {                       // X fp32 -> bf16, 8192*256 float4 groups
    int i = bx * 256 + t;
    float4 f = reinterpret_cast<const float4*>(X)[i];
    ushort4 o;
    o.x = f2bf(f.x); o.y = f2bf(f.y); o.z = f2bf(f.z); o.w = f2bf(f.w);
    reinterpret_cast<ushort4*>(Xb)[i] = o;
  } else if (bx < 12288) {               // weight transpose: 4 weights x 1024 tiles
    int tz = bx - 8192;
    int z = tz >> 10;
    int xy = tz & 1023;
    int bxt = xy & 31, byt = xy >> 5;
    const float* w = (z == 0) ? w0 : (z == 1) ? w1 : (z == 2) ? w2 : w3;
    const float sc = (z == 0) ? QSCALE : 1.0f;
    ushort* o = WT + (size_t)z * D_MODEL * D_MODEL;
    int tx = t & 31, ty = t >> 5;
    int x = bxt * 32 + tx;
    int y0 = byt * 32;
    #pragma unroll
    for (int i = ty; i < 32; i += 8)
      tile[i][tx] = w[(size_t)(y0 + i) * D_MODEL + x];
    __syncthreads();
    #pragma unroll
    for (int i = ty; i < 32; i += 8)
      o[(size_t)(bxt * 32 + i) * D_MODEL + y0 + tx] = f2bf(tile[tx][i] * sc);
  } else {                               // bias concat (12 blocks)
    int i = (bx - 12288) * 256 + t;
    bcat[i] = (i < 1024) ? bq[i] * QSCALE : (i < 2048) ? bk[i - 1024] : bv[i - 2048];
  }
}

#define MFMA16(a, b, c) __builtin_amdgcn_mfma_f32_16x16x32_bf16(a, b, c, 0, 0, 0)

// ---------- 128x128 2-phase GEMM, 2 blocks/CU: 256 threads (4 waves, 2Mx2N), BK=64 dbuf ----------
// LDS = A 2x16KB + B 2x16KB = 64KB -> TWO independent blocks per CU (the latency-hiding lever:
// when one block sits at a barrier/vmcnt, the other issues). 2 barriers per K-tile (entry + mid).
// T2 3-bit XOR swizzle both-sides (physical chunk = logical ^ (row&7)); counted vmcnt with no
// wait ever targeting a same-phase load:
//   calls/K-tile: A0..A3 (32 rows each), B0..B3.  Reads: P0 = af(all A) + bfr ni{0,1}
//   (per-wave rows: wc0 -> B0, wc1 -> B2); P1 = bfr ni{2,3} (B1 | B3).
//   Issue: P0 stages A0,A1,A2,A3,B0,B2 (6); P1 stages B1,B3 (2).
//   W0 (end P0) = vmcnt(6): retires B1,B3(kt) issued one phase earlier.
//   W1 (end P1) = vmcnt(2): retires the 6 issued in P0 of this tile.
// Grids are exact multiples of 256 and of 8 (XCD swizzle): qkv 24x64=1536, proj 8x64=512.
template <int BN, bool F32OUT>
__global__ __launch_bounds__(256, 2) void gemm2p(const ushort* __restrict__ A,
                                                 const ushort* __restrict__ BT,
                                                 const float* __restrict__ bias,
                                                 ushort* __restrict__ QK,
                                                 ushort* __restrict__ Vt,
                                                 float* __restrict__ Cf) {
  static_assert(BN == 128, "gemm2p tuned for BN=128");
  constexpr int BB = BN * 128;                          // 16384 B per B K-tile buffer
  __shared__ __align__(16) char smem[32768 + 2 * BB];   // [0,32K)=A bufs, [32K,64K)=B bufs
  const int tid  = threadIdx.x;
  const int w    = tid >> 6, lane = tid & 63;
  const int lo   = lane & 15, quad = lane >> 4;
  const int wr   = w >> 1, wc = w & 1;

  // XCD-aware bijective swizzle (nwg % 8 == 0)
  const int nx   = gridDim.x;
  const int nwg  = nx * gridDim.y;
  const int orig = blockIdx.y * nx + blockIdx.x;
  const int wg   = (orig & 7) * (nwg >> 3) + (orig >> 3);
  const int m0   = (wg / nx) * 128;
  const int n0   = (wg % nx) * BN;

  // staging: thread t writes linear LDS chunk t of each 4KB call (32 rows x 128B);
  // physical chunk (row, pc) holds logical (row, pc ^ (row&7)) -> source chunk = tid ^ ((tid>>3)&7)
  const int tl = tid ^ ((tid >> 3) & 7);
  const ushort* sA = A  + (size_t)(m0 + (tl >> 3)) * 1024 + (tl & 7) * 8;
  const ushort* sB = BT + (size_t)(n0 + (tl >> 3)) * 1024 + (tl & 7) * 8;
  char* lwA = smem + w * 1024;                 // + nb + call*4096 per call
  char* lwB = smem + 32768 + w * 1024;

  // swizzled ds_read: addr = row*128 + ((ks*64 + quad*16) ^ ((row&7)<<4)); row&7 == lo&7
  const int o0 = (quad * 16) ^ ((lo & 7) << 4);
  const int o1 = o0 ^ 64;
  const int rdA = (wr * 64 + lo) * 128;            // + bA + mi*2048 + o{0,1}
  const int rdB = 32768 + (wc * 64 + lo) * 128;    // + bB + ni*2048 + o{0,1}

  f32x4 acc[4][4];
  #pragma unroll
  for (int i = 0; i < 4; ++i)
    #pragma unroll
    for (int j = 0; j < 4; ++j) acc[i][j] = {0.f, 0.f, 0.f, 0.f};

  // ---- prologue: stage tile 0 into buf 0 (order: P0 set then P1 set) ----
  gload_lds16(sA,             lwA);              // A0 (rows 0-31)
  gload_lds16(sA + 32 * 1024, lwA + 4096);       // A1 (32-63)
  gload_lds16(sA + 64 * 1024, lwA + 8192);       // A2 (64-95)
  gload_lds16(sA + 96 * 1024, lwA + 12288);      // A3 (96-127)
  gload_lds16(sB,             lwB);              // B0 (0-31)
  gload_lds16(sB + 64 * 1024, lwB + 8192);       // B2 (64-95)
  gload_lds16(sB + 32 * 1024, lwB + 4096);       // B1 (32-63)
  gload_lds16(sB + 96 * 1024, lwB + 12288);      // B3 (96-127)
  asm volatile("s_waitcnt vmcnt(2)" ::: "memory");  // B1,B3 stay in flight (read in P1)
  __builtin_amdgcn_s_barrier();
  asm volatile("" ::: "memory");

  const char* L = smem;
  #pragma unroll 2
  for (int kt = 0; kt < 16; ++kt) {
    const int bA = (kt & 1) << 14;
    const int bB = (kt & 1) * BB;
    const int nA = bA ^ 16384;
    const int nB = bB ^ BB;
    const int kc = (kt + 1) * 64;
    const bool pf = kt < 15;
    bf16x8 af[4][2], bfr[2][2];

    // ================ P0: af all + bfr ni{0,1}; stage A0-3,B0,B2 ================
    #pragma unroll
    for (int mi = 0; mi < 4; ++mi) {
      af[mi][0] = *(const bf16x8*)(L + bA + rdA + mi * 2048 + o0);
      af[mi][1] = *(const bf16x8*)(L + bA + rdA + mi * 2048 + o1);
    }
    #pragma unroll
    for (int j = 0; j < 2; ++j) {
      bfr[j][0] = *(const bf16x8*)(L + bB + rdB + j * 2048 + o0);
      bfr[j][1] = *(const bf16x8*)(L + bB + rdB + j * 2048 + o1);
    }
    if (pf) {
      gload_lds16(sA + kc,             lwA + nA);
      gload_lds16(sA + 32 * 1024 + kc, lwA + nA + 4096);
      gload_lds16(sA + 64 * 1024 + kc, lwA + nA + 8192);
      gload_lds16(sA + 96 * 1024 + kc, lwA + nA + 12288);
      gload_lds16(sB + kc,             lwB + nB);
      gload_lds16(sB + 64 * 1024 + kc, lwB + nB + 8192);
    }
    asm volatile("s_waitcnt lgkmcnt(0)" ::: "memory");
    __builtin_amdgcn_sched_barrier(0);
    __builtin_amdgcn_s_setprio(1);
    #pragma unroll
    for (int ks = 0; ks < 2; ++ks)
      #pragma unroll
      for (int mi = 0; mi < 4; ++mi) {
        acc[mi][0] = MFMA16(af[mi][ks], bfr[0][ks], acc[mi][0]);
        acc[mi][1] = MFMA16(af[mi][ks], bfr[1][ks], acc[mi][1]);
      }
    __builtin_amdgcn_s_setprio(0);
    if (pf) asm volatile("s_waitcnt vmcnt(6)" ::: "memory");   // retire B1,B3(kt)
    else    asm volatile("s_waitcnt vmcnt(0)" ::: "memory");
    __builtin_amdgcn_s_barrier();
    asm volatile("" ::: "memory");

    // ================ P1: bfr ni{2,3}; stage B1,B3 ================
    #pragma unroll
    for (int j = 0; j < 2; ++j) {
      bfr[j][0] = *(const bf16x8*)(L + bB + rdB + (2 + j) * 2048 + o0);
      bfr[j][1] = *(const bf16x8*)(L + bB + rdB + (2 + j) * 2048 + o1);
    }
    if (pf) {
      gload_lds16(sB + 32 * 1024 + kc, lwB + nB + 4096);
      gload_lds16(sB + 96 * 1024 + kc, lwB + nB + 12288);
    }
    asm volatile("s_waitcnt lgkmcnt(0)" ::: "memory");
    __builtin_amdgcn_sched_barrier(0);
    __builtin_amdgcn_s_setprio(1);
    #pragma unroll
    for (int ks = 0; ks < 2; ++ks)
      #pragma unroll
      for (int mi = 0; mi < 4; ++mi) {
        acc[mi][2] = MFMA16(af[mi][ks], bfr[0][ks], acc[mi][2]);
        acc[mi][3] = MFMA16(af[mi][ks], bfr[1][ks], acc[mi][3]);
      }
    __builtin_amdgcn_s_setprio(0);
    if (pf) {
      asm volatile("s_waitcnt vmcnt(2)" ::: "memory");   // retire A0-3,B0,B2(kt+1); B1,B3 fly
      __builtin_amdgcn_s_barrier();
      asm volatile("" ::: "memory");
    }
  }

  // ---- epilogue ----
  if constexpr (F32OUT) {
    #pragma unroll
    for (int ni = 0; ni < 4; ++ni) {
      const int col = n0 + wc * 64 + ni * 16 + lo;
      const float bv = bias[col];
      #pragma unroll
      for (int mi = 0; mi < 4; ++mi) {
        const int row = m0 + wr * 64 + mi * 16 + quad * 4;
        #pragma unroll
        for (int r = 0; r < 4; ++r)
          Cf[(size_t)(row + r) * 1024 + col] = acc[mi][ni][r] + bv;
      }
    }
  } else if (n0 < 2048) {
    // Q,K part: dense [8192][2048] store (2048 % 128 == 0 -> branch block-uniform)
    #pragma unroll
    for (int ni = 0; ni < 4; ++ni) {
      const int col = n0 + wc * 64 + ni * 16 + lo;
      const float bv = bias[col];
      #pragma unroll
      for (int mi = 0; mi < 4; ++mi) {
        const int row = m0 + wr * 64 + mi * 16 + quad * 4;
        #pragma unroll
        for (int r = 0; r < 4; ++r)
          QK[(size_t)(row + r) * 2048 + col] = f2bf(acc[mi][ni][r] + bv);
      }
    }
  } else {
    // V part: permuted-transpose store into Vt[b][h][d][SEQ]
    #pragma unroll
    for (int ni = 0; ni < 4; ++ni) {
      const int col  = n0 + wc * 64 + ni * 16 + lo;
      const int vcol = col - 2048;
      const int hh = vcol >> 6, d = vcol & 63;
      const float bv = bias[col];
      #pragma unroll
      for (int mi = 0; mi < 4; ++mi) {
        const int base = m0 + wr * 64 + mi * 16;         // multiple of 16
        const int brow = base + quad * 4;                // 4 keys brow..brow+3
        const int bidx = brow >> 11;                     // batch
        const int srow = brow & 2047;                    // seq within batch
        const int ck   = srow >> 6;
        const int c0   = (base & 32) + (quad << 3) + ((base >> 2) & 4);
        ushort e0 = f2bf(acc[mi][ni][0] + bv);
        ushort e1 = f2bf(acc[mi][ni][1] + bv);
        ushort e2 = f2bf(acc[mi][ni][2] + bv);
        ushort e3 = f2bf(acc[mi][ni][3] + bv);
        uint2 pk;
        pk.x = (uint)e0 | ((uint)e1 << 16);
        pk.y = (uint)e2 | ((uint)e3 << 16);
        *(uint2*)&Vt[(size_t)((bidx * HEADS + hh) * HDIM + d) * SEQ + ck * 64 + c0] = pk;
      }
    }
  }
}

// ---------- flash attention (R4 structure, best measured): block = 256 q rows, wave = 64 q ----------
// S^T via mfma(A=K,B=Q); exp'd scores feed PV A-operand directly from registers.
// Double-buffered K/V staging with counted vmcnt (T3/T14); XCD-grouped K/V reuse (T1);
// setprio around the PV MFMA cluster (T5).
__global__ __launch_bounds__(256, 2) void attn_kernel(const ushort* __restrict__ QK,
                                                      const ushort* __restrict__ Vt,
                                                      ushort* __restrict__ Og) {
  __shared__ __align__(16) ushort Ks[2][64 * 64];   // [buf][key][64 d], seg-swizzled
  __shared__ __align__(16) ushort Vs[2][64 * 64];   // [buf][d][64 key-slots], seg-swizzled

  const int tid  = threadIdx.x;
  const int w    = tid >> 6, lane = tid & 63;
  const int lo   = lane & 15, quad = lane >> 4;

  // XCD remap: p -> (G, qb); bijective, p&7 == G&7 (8 q-blocks of a group share an XCD)
  const int p  = blockIdx.x + (blockIdx.y << 3) + (blockIdx.z << 7);
  const int G  = ((p >> 6) << 3) | (p & 7);
  const int h  = G & 15, b = G >> 4;
  const int qbase = ((p >> 3) & 7) * 256 + w * 64;
  const int swz = lo & 7;

  // per-thread staging geometry (4 gload_lds16 per chunk: K0,V0,K1,V1)
  auto STAGE = [&](int buf, int ck) {
    #pragma unroll
    for (int i = 0; i < 2; ++i) {
      const int c16 = (w * 2 + i) * 64 + lane;
      const int r = c16 >> 3, ps = c16 & 7;
      const int gs = ps ^ (r & 7);
      gload_lds16(QK + (size_t)(b * SEQ + ck * 64 + r) * 2048 + 1024 + h * HDIM + gs * 8,
                  &Ks[buf][(w * 2 + i) * 512]);
      gload_lds16(Vt + (size_t)((b * HEADS + h) * HDIM + r) * SEQ + ck * 64 + gs * 8,
                  &Vs[buf][(w * 2 + i) * 512]);
    }
  };

  // Q fragments (B-operand layout: n=lo, k=quad*8+j); pre-scaled by QSCALE via Wq
  bf16x8 qf[4][2];
  #pragma unroll
  for (int qg = 0; qg < 4; ++qg) {
    const ushort* qp = QK + (size_t)(b * SEQ + qbase + qg * 16 + lo) * 2048 + h * HDIM;
    qf[qg][0] = *(const bf16x8*)(qp + quad * 8);
    qf[qg][1] = *(const bf16x8*)(qp + 32 + quad * 8);
  }

  f32x4 acc[4][4];
  #pragma unroll
  for (int qg = 0; qg < 4; ++qg)
    #pragma unroll
    for (int t = 0; t < 4; ++t) acc[qg][t] = {0.f, 0.f, 0.f, 0.f};
  float lsum[4] = {0.f, 0.f, 0.f, 0.f};

  // prologue: stage chunk 0 into buf 0; drain everything (incl. Q loads) once
  STAGE(0, 0);
  __syncthreads();

  #pragma unroll 2
  for (int ck = 0; ck < SEQ / 64; ++ck) {
    const int cur = ck & 1;
    if (ck < SEQ / 64 - 1) {
      STAGE(cur ^ 1, ck + 1);                           // issue-early (T14)
      asm volatile("s_waitcnt vmcnt(4)" ::: "memory");  // wait cur; next stays in flight
    } else {
      asm volatile("s_waitcnt vmcnt(0)" ::: "memory");
    }
    __builtin_amdgcn_s_barrier();
    asm volatile("" ::: "memory");

    // --- phase A: K fragments resident, S^T per q-group, exp + pack in registers ---
    bf16x8 kf[4][2];
    #pragma unroll
    for (int sub = 0; sub < 4; ++sub) {
      const ushort* kr = &Ks[cur][(sub * 16 + lo) * 64];
      kf[sub][0] = *(const bf16x8*)(kr + ((quad ^ swz) * 8));
      kf[sub][1] = *(const bf16x8*)(kr + (((4 + quad) ^ swz) * 8));
    }

    bf16x8 af[4][2];
    #pragma unroll
    for (int qg = 0; qg < 4; ++qg) {
      f32x4 s[4];
      #pragma unroll
      for (int sub = 0; sub < 4; ++sub) s[sub] = {0.f, 0.f, 0.f, 0.f};
      #pragma unroll
      for (int sub = 0; sub < 4; ++sub) {
        s[sub] = __builtin_amdgcn_mfma_f32_16x16x32_bf16(kf[sub][0], qf[qg][0], s[sub], 0, 0, 0);
        s[sub] = __builtin_amdgcn_mfma_f32_16x16x32_bf16(kf[sub][1], qf[qg][1], s[sub], 0, 0, 0);
      }
      float p2[4][4];
      #pragma unroll
      for (int sub = 0; sub < 4; ++sub)
        #pragma unroll
        for (int r = 0; r < 4; ++r) p2[sub][r] = __builtin_amdgcn_exp2f(s[sub][r]);
      float t0 = 0.f;
      #pragma unroll
      for (int sub = 0; sub < 4; ++sub)
        t0 += (p2[sub][0] + p2[sub][1]) + (p2[sub][2] + p2[sub][3]);
      lsum[qg] += t0;
      af[qg][0] = pack8(p2[0][0], p2[0][1], p2[0][2], p2[0][3], p2[1][0], p2[1][1], p2[1][2], p2[1][3]);
      af[qg][1] = pack8(p2[2][0], p2[2][1], p2[2][2], p2[2][3], p2[3][0], p2[3][1], p2[3][2], p2[3][3]);
    }

    // --- phase B: PV (A = exp'd scores from registers, B = V^T from LDS) ---
    __builtin_amdgcn_s_setprio(1);
    #pragma unroll
    for (int t = 0; t < 4; ++t) {
      const ushort* vr = &Vs[cur][(t * 16 + lo) * 64];
      #pragma unroll
      for (int hh = 0; hh < 2; ++hh) {
        bf16x8 vf = *(const bf16x8*)(vr + (((hh * 4 + quad) ^ swz) * 8));
        #pragma unroll
        for (int qg = 0; qg < 4; ++qg)
          acc[qg][t] = __builtin_amdgcn_mfma_f32_16x16x32_bf16(af[qg][hh], vf, acc[qg][t], 0, 0, 0);
      }
    }
    __builtin_amdgcn_s_setprio(0);

    asm volatile("" ::: "memory");
    __builtin_amdgcn_s_barrier();   // all reads of buf cur done before it is restaged
    asm volatile("" ::: "memory");
  }

  // --- epilogue: lsum lives at lane lo = q; reduce across quads, redistribute, store ---
  #pragma unroll
  for (int qg = 0; qg < 4; ++qg) {
    float v = lsum[qg];
    v += __shfl_xor(v, 16);
    v += __shfl_xor(v, 32);
    float linv[4];
    #pragma unroll
    for (int r = 0; r < 4; ++r) linv[r] = 1.0f / __shfl(v, quad * 4 + r);
    #pragma unroll
    for (int t = 0; t < 4; ++t)
      #pragma unroll
      for (int r = 0; r < 4; ++r)
        Og[(size_t)(b * SEQ + qbase + qg * 16 + quad * 4 + r) * D_MODEL + h * HDIM + t * 16 + lo] =
            f2bf(acc[qg][t][r] * linv[r]);
  }
}

extern "C" void kernel_launch(void* const* d_in, const int* in_sizes, int n_in,
                              void* d_out, int out_size, void* d_ws, size_t ws_size,
                              hipStream_t stream) {
  const float* X  = (const float*)d_in[0];
  const float* Wq = (const float*)d_in[1];
  const float* bq = (const float*)d_in[2];
  const float* Wk = (const float*)d_in[3];
  const float* bk = (const float*)d_in[4];
  const float* Wv = (const float*)d_in[5];
  const float* bv = (const float*)d_in[6];
  const float* Wo = (const float*)d_in[7];
  const float* bo = (const float*)d_in[8];
  float* out = (float*)d_out;
  char* ws = (char*)d_ws;

  // workspace (88 MB):
  //   [0,16M)   Xb  (bf16 X)
  //   [16,24M)  WT  (4x bf16 transposed weights q|k|v|o; Wq pre-scaled)
  //   [24,56M)  QK  bf16 [8192][2048]
  //   [56,72M)  Vt  bf16 [b][h][64][2048] (permuted keys)
  //   [72,88M)  Ob  bf16 [8192][1024]; head transiently holds bcat (dead before attn writes Ob)
  ushort* Xb  = (ushort*)(ws);
  ushort* WT  = (ushort*)(ws + 16777216);
  ushort* QKb = (ushort*)(ws + 25165824);
  ushort* Vtb = (ushort*)(ws + 58720256);
  ushort* Ob  = (ushort*)(ws + 75497472);
  float*  bcat = (float*)(ws + 75497472);
  const int WSTRIDE = D_MODEL * D_MODEL;

  // 1) fused prep: X->bf16, weight transposes, bias concat
  prep_kernel<<<12300, 256, 0, stream>>>(X, Wq, Wk, Wv, Wo, bq, bk, bv, Xb, WT, bcat);

  // 2) fused QKV projection: 128x128 tiles, 2 blocks/CU -> 1536 blocks = 6 exact rounds
  gemm2p<128, false><<<dim3(24, 64), 256, 0, stream>>>(Xb, WT, bcat, QKb, Vtb, nullptr);

  // 3) flash attention (R4: dbuf staging + counted vmcnt + XCD-grouped K/V reuse)
  attn_kernel<<<dim3(SEQ / 256, HEADS, BATCH), 256, 0, stream>>>(QKb, Vtb, Ob);

  // 4) output projection: 128x128 tiles -> 512 blocks = 2 exact rounds, fp32 out + bias
  gemm2p<128, true><<<dim3(8, 64), 256, 0, stream>>>(Ob, WT + 3 * WSTRIDE, bo, nullptr, nullptr, out);
}